// Round 1
// baseline (243.063 us; speedup 1.0000x reference)
//
#include <hip/hip_runtime.h>
#include <stdint.h>

// SVDQuant forward on MI355X:
//   y = Q4(x*smooth) @ Q4(Wres)^T + (x*smooth) @ lora_down @ lora_up^T + bias
// Plan:
//   K0 ldt_kernel:     lora_down [2048,32] f32  -> ldT [32,2048] bf16 (transposed)
//   K1 quant_x_kernel: Xcat[m][0:2048]  = bf16(fakequant(x*smooth)), pad [2080:2112]=0
//   Kw quant_w_kernel: Wcat[n][0:2048]  = bf16(fakequant(Wres)), [2048:2080]=bf16(lora_up), pad=0
//   K2 lowrank_kernel: t = (x*smooth) @ lora_down (MFMA, k-split across 4 waves)
//                      -> Xcat[m][2048:2080] = bf16(t)
//   K3 gemm_kernel:    out = Xcat @ Wcat^T + bias   (K = 2112, m97-style MFMA GEMM
//                      with global_load_lds width-16 staging + XOR swizzle)

typedef __attribute__((ext_vector_type(8))) short short8;
typedef __attribute__((ext_vector_type(8))) unsigned short ushort8;
typedef __attribute__((ext_vector_type(4))) float floatx4;

#define M_TOK 8192
#define K_IN  2048
#define N_OUT 2048
#define RANK  32
#define KC    2112   // 2048 quant + 32 lowrank + 32 zero pad  (33 * 64)

// round-to-nearest-even f32 -> bf16 (finite inputs only)
__device__ __forceinline__ unsigned short f2bf(float f) {
  unsigned int u = __float_as_uint(f);
  u += 0x7fff + ((u >> 16) & 1);
  return (unsigned short)(u >> 16);
}

// ---------------- K0: transpose+convert lora_down -> ldT [32][2048] bf16 ----
__global__ __launch_bounds__(256) void ldt_kernel(const float* __restrict__ ld,
                                                  unsigned short* __restrict__ ldT) {
  int i = blockIdx.x * 256 + threadIdx.x;  // 0 .. 32*2048-1
  int r = i >> 11;
  int k = i & 2047;
  ldT[r * K_IN + k] = f2bf(ld[k * RANK + r]);
}

// ---------------- K1: fake-quant x*smooth -> Xcat[:, 0:2048] ---------------
__global__ __launch_bounds__(256) void quant_x_kernel(const float* __restrict__ x,
                                                      const float* __restrict__ smooth,
                                                      unsigned short* __restrict__ Xcat) {
  int row = blockIdx.x, tid = threadIdx.x;
  const float4* xr = (const float4*)(x + (size_t)row * K_IN);
  const float4* sr = (const float4*)smooth;
  float4 a0 = xr[tid * 2], a1 = xr[tid * 2 + 1];
  float4 s0 = sr[tid * 2], s1 = sr[tid * 2 + 1];
  float v[8] = {a0.x * s0.x, a0.y * s0.y, a0.z * s0.z, a0.w * s0.w,
                a1.x * s1.x, a1.y * s1.y, a1.z * s1.z, a1.w * s1.w};
  float amax = 0.f;
#pragma unroll
  for (int i = 0; i < 8; ++i) amax = fmaxf(amax, fabsf(v[i]));
  // group of 64 elems = 8 consecutive lanes
  amax = fmaxf(amax, __shfl_xor(amax, 1, 64));
  amax = fmaxf(amax, __shfl_xor(amax, 2, 64));
  amax = fmaxf(amax, __shfl_xor(amax, 4, 64));
  float scale = fmaxf(amax / 7.0f, 1e-8f);
  ushort8 q;
#pragma unroll
  for (int i = 0; i < 8; ++i) {
    float qq = rintf(v[i] / scale);          // IEEE div + RNE == jnp.round(g/scale)
    qq = fminf(fmaxf(qq, -7.f), 7.f);
    q[i] = f2bf(qq * scale);
  }
  *(ushort8*)(Xcat + (size_t)row * KC + tid * 8) = q;
  if (tid < 32) Xcat[(size_t)row * KC + 2080 + tid] = 0;  // zero pad
}

// ---------------- Kw: fake-quant Wres -> Wcat[:,0:2048], append lora_up ----
__global__ __launch_bounds__(256) void quant_w_kernel(const float* __restrict__ wgt,
                                                      const float* __restrict__ lup,
                                                      unsigned short* __restrict__ Wcat) {
  int row = blockIdx.x, tid = threadIdx.x;
  const float4* wr = (const float4*)(wgt + (size_t)row * K_IN);
  float4 a0 = wr[tid * 2], a1 = wr[tid * 2 + 1];
  float v[8] = {a0.x, a0.y, a0.z, a0.w, a1.x, a1.y, a1.z, a1.w};
  float amax = 0.f;
#pragma unroll
  for (int i = 0; i < 8; ++i) amax = fmaxf(amax, fabsf(v[i]));
  amax = fmaxf(amax, __shfl_xor(amax, 1, 64));
  amax = fmaxf(amax, __shfl_xor(amax, 2, 64));
  amax = fmaxf(amax, __shfl_xor(amax, 4, 64));
  float scale = fmaxf(amax / 7.0f, 1e-8f);
  ushort8 q;
#pragma unroll
  for (int i = 0; i < 8; ++i) {
    float qq = rintf(v[i] / scale);
    qq = fminf(fmaxf(qq, -7.f), 7.f);
    q[i] = f2bf(qq * scale);
  }
  *(ushort8*)(Wcat + (size_t)row * KC + tid * 8) = q;
  if (tid < 32)      Wcat[(size_t)row * KC + 2048 + tid] = f2bf(lup[row * RANK + tid]);
  else if (tid < 64) Wcat[(size_t)row * KC + 2048 + tid] = 0;
}

// ---------------- K2: t = (x*smooth) @ lora_down -> Xcat[:,2048:2080] ------
// block: 256 thr = 4 waves, 64 rows; each wave covers K/4 = 512, LDS reduce.
__global__ __launch_bounds__(256) void lowrank_kernel(const float* __restrict__ x,
                                                      const float* __restrict__ smooth,
                                                      const unsigned short* __restrict__ ldT,
                                                      unsigned short* __restrict__ Xcat) {
  __shared__ float red[4][64][32];  // 32 KiB
  int tid = threadIdx.x;
  int w = tid >> 6, lane = tid & 63, quad = lane >> 4, l16 = lane & 15;
  int rowbase = blockIdx.x * 64;
  floatx4 acc[4][2];
#pragma unroll
  for (int mt = 0; mt < 4; ++mt)
#pragma unroll
    for (int nt = 0; nt < 2; ++nt) acc[mt][nt] = (floatx4)0.f;
  int kbase = w * 512;
  for (int it = 0; it < 16; ++it) {
    int k = kbase + it * 32 + quad * 8;
    float4 sm0 = *(const float4*)(smooth + k);
    float4 sm1 = *(const float4*)(smooth + k + 4);
    short8 bfrag[2];
#pragma unroll
    for (int nt = 0; nt < 2; ++nt)
      bfrag[nt] = *(const short8*)(ldT + (size_t)(nt * 16 + l16) * K_IN + k);
#pragma unroll
    for (int mt = 0; mt < 4; ++mt) {
      const float* xr = x + (size_t)(rowbase + mt * 16 + l16) * K_IN + k;
      float4 x0 = *(const float4*)xr;
      float4 x1 = *(const float4*)(xr + 4);
      short8 af;
      af[0] = (short)f2bf(x0.x * sm0.x); af[1] = (short)f2bf(x0.y * sm0.y);
      af[2] = (short)f2bf(x0.z * sm0.z); af[3] = (short)f2bf(x0.w * sm0.w);
      af[4] = (short)f2bf(x1.x * sm1.x); af[5] = (short)f2bf(x1.y * sm1.y);
      af[6] = (short)f2bf(x1.z * sm1.z); af[7] = (short)f2bf(x1.w * sm1.w);
#pragma unroll
      for (int nt = 0; nt < 2; ++nt)
        acc[mt][nt] = __builtin_amdgcn_mfma_f32_16x16x32_bf16(af, bfrag[nt], acc[mt][nt], 0, 0, 0);
    }
  }
#pragma unroll
  for (int mt = 0; mt < 4; ++mt)
#pragma unroll
    for (int nt = 0; nt < 2; ++nt)
#pragma unroll
      for (int r = 0; r < 4; ++r)
        red[w][mt * 16 + quad * 4 + r][nt * 16 + l16] = acc[mt][nt][r];
  __syncthreads();
  int rl = tid >> 2, seg = tid & 3;
  ushort8 o;
#pragma unroll
  for (int j = 0; j < 8; ++j) {
    int r = seg * 8 + j;
    float s = red[0][rl][r] + red[1][rl][r] + red[2][rl][r] + red[3][rl][r];
    o[j] = f2bf(s);
  }
  *(ushort8*)(Xcat + (size_t)(rowbase + rl) * KC + 2048 + seg * 8) = o;
}

// ---------------- K3: main GEMM: out = Xcat @ Wcat^T + bias ----------------
__device__ __forceinline__ void gld_lds16(const unsigned short* g, unsigned short* l) {
  __builtin_amdgcn_global_load_lds(
      (const __attribute__((address_space(1))) unsigned int*)g,
      (__attribute__((address_space(3))) unsigned int*)l, 16, 0, 0);
}

__global__ __launch_bounds__(256) void gemm_kernel(const unsigned short* __restrict__ Xcat,
                                                   const unsigned short* __restrict__ Wcat,
                                                   const float* __restrict__ bias,
                                                   float* __restrict__ out) {
  __shared__ unsigned short smem[16384];  // A: 128x64, B: 128x64 bf16 (32 KiB)
  unsigned short* smemA = smem;
  unsigned short* smemB = smem + 8192;
  int tid = threadIdx.x;
  int w = tid >> 6, lane = tid & 63, quad = lane >> 4, l16 = lane & 15;
  int wm = w >> 1, wn = w & 1;
  int bM = blockIdx.y * 128, bN = blockIdx.x * 128;

  // staging: thread -> (row = tid/8, chunk pos = tid%8), fetch XOR-swizzled chunk
  int srow = tid >> 3;
  int cs = (tid & 7) ^ (srow & 7);
  const unsigned short* Ag = Xcat + (size_t)(bM + srow) * KC + cs * 8;
  const unsigned short* Bg = Wcat + (size_t)(bN + srow) * KC + cs * 8;

  // fragment LDS offsets (ushort units). row&7 == l16&7 for all tiles.
  int c0 = (quad ^ (l16 & 7)) * 8;
  int c1 = ((4 + quad) ^ (l16 & 7)) * 8;
  int arow[4], brow[4];
#pragma unroll
  for (int mt = 0; mt < 4; ++mt) arow[mt] = (wm * 64 + mt * 16 + l16) * 64;
#pragma unroll
  for (int nt = 0; nt < 4; ++nt) brow[nt] = (wn * 64 + nt * 16 + l16) * 64;

  floatx4 acc[4][4];
#pragma unroll
  for (int mt = 0; mt < 4; ++mt)
#pragma unroll
    for (int nt = 0; nt < 4; ++nt) acc[mt][nt] = (floatx4)0.f;

  for (int kt = 0; kt < 33; ++kt) {
    int k0 = kt * 64;
#pragma unroll
    for (int rd = 0; rd < 4; ++rd) {
      gld_lds16(Ag + (size_t)rd * 32 * KC + k0, smemA + rd * 2048 + w * 512);
      gld_lds16(Bg + (size_t)rd * 32 * KC + k0, smemB + rd * 2048 + w * 512);
    }
    __syncthreads();  // drains vmcnt (global_load_lds) before reads

    short8 af[4][2], bf[4][2];
#pragma unroll
    for (int mt = 0; mt < 4; ++mt) {
      af[mt][0] = *(const short8*)(smemA + arow[mt] + c0);
      af[mt][1] = *(const short8*)(smemA + arow[mt] + c1);
    }
#pragma unroll
    for (int nt = 0; nt < 4; ++nt) {
      bf[nt][0] = *(const short8*)(smemB + brow[nt] + c0);
      bf[nt][1] = *(const short8*)(smemB + brow[nt] + c1);
    }
#pragma unroll
    for (int kb = 0; kb < 2; ++kb)
#pragma unroll
      for (int mt = 0; mt < 4; ++mt)
#pragma unroll
        for (int nt = 0; nt < 4; ++nt)
          acc[mt][nt] = __builtin_amdgcn_mfma_f32_16x16x32_bf16(af[mt][kb], bf[nt][kb],
                                                                acc[mt][nt], 0, 0, 0);
    __syncthreads();  // protect LDS before next stage
  }

  // epilogue: + bias, store fp32
#pragma unroll
  for (int nt = 0; nt < 4; ++nt) {
    int col = bN + wn * 64 + nt * 16 + l16;
    float bv = bias[col];
#pragma unroll
    for (int mt = 0; mt < 4; ++mt) {
      int row = bM + wm * 64 + mt * 16 + quad * 4;
#pragma unroll
      for (int r = 0; r < 4; ++r)
        out[(size_t)(row + r) * N_OUT + col] = acc[mt][nt][r] + bv;
    }
  }
}

extern "C" void kernel_launch(void* const* d_in, const int* in_sizes, int n_in,
                              void* d_out, int out_size, void* d_ws, size_t ws_size,
                              hipStream_t stream) {
  const float* x      = (const float*)d_in[0];
  const float* wgt    = (const float*)d_in[1];
  const float* ld     = (const float*)d_in[2];
  const float* lup    = (const float*)d_in[3];
  const float* smooth = (const float*)d_in[4];
  const float* bias   = (const float*)d_in[5];
  float* out = (float*)d_out;

  unsigned short* Xcat = (unsigned short*)d_ws;                 // 8192*2112*2 = 34.6 MB
  unsigned short* Wcat = Xcat + (size_t)M_TOK * KC;             //  8.65 MB
  unsigned short* ldT  = Wcat + (size_t)N_OUT * KC;             //  128 KB

  hipLaunchKernelGGL(ldt_kernel,     dim3(256),    dim3(256), 0, stream, ld, ldT);
  hipLaunchKernelGGL(quant_x_kernel, dim3(M_TOK),  dim3(256), 0, stream, x, smooth, Xcat);
  hipLaunchKernelGGL(quant_w_kernel, dim3(N_OUT),  dim3(256), 0, stream, wgt, lup, Wcat);
  hipLaunchKernelGGL(lowrank_kernel, dim3(M_TOK/64), dim3(256), 0, stream, x, smooth, ldT, Xcat);
  hipLaunchKernelGGL(gemm_kernel,    dim3(N_OUT/128, M_TOK/128), dim3(256), 0, stream,
                     Xcat, Wcat, bias, out);
}

// Round 2
// 238.990 us; speedup vs baseline: 1.0170x; 1.0170x over previous
//
#include <hip/hip_runtime.h>
#include <stdint.h>

// SVDQuant forward on MI355X:
//   y = Q4(x*smooth) @ Q4(Wres)^T + (x*smooth) @ lora_down @ lora_up^T + bias
// Plan:
//   K0 ldt_kernel:     lora_down [2048,32] f32  -> ldT [32,2048] bf16 (transposed)
//   K1 quant_x_kernel: Xcat[m][0:2048]  = bf16(fakequant(x*smooth)), pad [2080:2112]=0
//   Kw quant_w_kernel: Wcat[n][0:2048]  = bf16(fakequant(Wres)), [2048:2080]=bf16(lora_up), pad=0
//   K2 lowrank_kernel: t = (x*smooth) @ lora_down (MFMA)  -> Xcat[m][2048:2080] = bf16(t)
//                      R2: 16 rows/block, 512 blocks (was 128 — half the CUs idle)
//   K3 gemm_kernel:    out = Xcat @ Wcat^T + bias   (K = 2112, m97-style MFMA GEMM
//                      with global_load_lds width-16 staging + XOR swizzle)

typedef __attribute__((ext_vector_type(8))) short short8;
typedef __attribute__((ext_vector_type(8))) unsigned short ushort8;
typedef __attribute__((ext_vector_type(4))) unsigned short ushort4v;
typedef __attribute__((ext_vector_type(4))) float floatx4;

#define M_TOK 8192
#define K_IN  2048
#define N_OUT 2048
#define RANK  32
#define KC    2112   // 2048 quant + 32 lowrank + 32 zero pad  (33 * 64)

// round-to-nearest-even f32 -> bf16 (finite inputs only)
__device__ __forceinline__ unsigned short f2bf(float f) {
  unsigned int u = __float_as_uint(f);
  u += 0x7fff + ((u >> 16) & 1);
  return (unsigned short)(u >> 16);
}

// ---------------- K0: transpose+convert lora_down -> ldT [32][2048] bf16 ----
__global__ __launch_bounds__(256) void ldt_kernel(const float* __restrict__ ld,
                                                  unsigned short* __restrict__ ldT) {
  int i = blockIdx.x * 256 + threadIdx.x;  // 0 .. 32*2048-1
  int r = i >> 11;
  int k = i & 2047;
  ldT[r * K_IN + k] = f2bf(ld[k * RANK + r]);
}

// ---------------- K1: fake-quant x*smooth -> Xcat[:, 0:2048] ---------------
__global__ __launch_bounds__(256) void quant_x_kernel(const float* __restrict__ x,
                                                      const float* __restrict__ smooth,
                                                      unsigned short* __restrict__ Xcat) {
  int row = blockIdx.x, tid = threadIdx.x;
  const float4* xr = (const float4*)(x + (size_t)row * K_IN);
  const float4* sr = (const float4*)smooth;
  float4 a0 = xr[tid * 2], a1 = xr[tid * 2 + 1];
  float4 s0 = sr[tid * 2], s1 = sr[tid * 2 + 1];
  float v[8] = {a0.x * s0.x, a0.y * s0.y, a0.z * s0.z, a0.w * s0.w,
                a1.x * s1.x, a1.y * s1.y, a1.z * s1.z, a1.w * s1.w};
  float amax = 0.f;
#pragma unroll
  for (int i = 0; i < 8; ++i) amax = fmaxf(amax, fabsf(v[i]));
  // group of 64 elems = 8 consecutive lanes
  amax = fmaxf(amax, __shfl_xor(amax, 1, 64));
  amax = fmaxf(amax, __shfl_xor(amax, 2, 64));
  amax = fmaxf(amax, __shfl_xor(amax, 4, 64));
  float scale = fmaxf(amax / 7.0f, 1e-8f);
  ushort8 q;
#pragma unroll
  for (int i = 0; i < 8; ++i) {
    float qq = rintf(v[i] / scale);          // IEEE div + RNE == jnp.round(g/scale)
    qq = fminf(fmaxf(qq, -7.f), 7.f);
    q[i] = f2bf(qq * scale);
  }
  *(ushort8*)(Xcat + (size_t)row * KC + tid * 8) = q;
  if (tid < 32) Xcat[(size_t)row * KC + 2080 + tid] = 0;  // zero pad
}

// ---------------- Kw: fake-quant Wres -> Wcat[:,0:2048], append lora_up ----
__global__ __launch_bounds__(256) void quant_w_kernel(const float* __restrict__ wgt,
                                                      const float* __restrict__ lup,
                                                      unsigned short* __restrict__ Wcat) {
  int row = blockIdx.x, tid = threadIdx.x;
  const float4* wr = (const float4*)(wgt + (size_t)row * K_IN);
  float4 a0 = wr[tid * 2], a1 = wr[tid * 2 + 1];
  float v[8] = {a0.x, a0.y, a0.z, a0.w, a1.x, a1.y, a1.z, a1.w};
  float amax = 0.f;
#pragma unroll
  for (int i = 0; i < 8; ++i) amax = fmaxf(amax, fabsf(v[i]));
  amax = fmaxf(amax, __shfl_xor(amax, 1, 64));
  amax = fmaxf(amax, __shfl_xor(amax, 2, 64));
  amax = fmaxf(amax, __shfl_xor(amax, 4, 64));
  float scale = fmaxf(amax / 7.0f, 1e-8f);
  ushort8 q;
#pragma unroll
  for (int i = 0; i < 8; ++i) {
    float qq = rintf(v[i] / scale);
    qq = fminf(fmaxf(qq, -7.f), 7.f);
    q[i] = f2bf(qq * scale);
  }
  *(ushort8*)(Wcat + (size_t)row * KC + tid * 8) = q;
  if (tid < 32)      Wcat[(size_t)row * KC + 2048 + tid] = f2bf(lup[row * RANK + tid]);
  else if (tid < 64) Wcat[(size_t)row * KC + 2048 + tid] = 0;
}

// ---------------- K2: t = (x*smooth) @ lora_down -> Xcat[:,2048:2080] ------
// R2: 512 blocks x 16 rows (was 128 x 64 — only half the CUs had work).
// 256 thr = 4 waves; wave w covers K range [w*512, w*512+512); LDS reduce.
__global__ __launch_bounds__(256) void lowrank_kernel(const float* __restrict__ x,
                                                      const float* __restrict__ smooth,
                                                      const unsigned short* __restrict__ ldT,
                                                      unsigned short* __restrict__ Xcat) {
  __shared__ float red[4][16][32];  // 8 KiB
  int tid = threadIdx.x;
  int w = tid >> 6, lane = tid & 63, quad = lane >> 4, l16 = lane & 15;
  int rowbase = blockIdx.x * 16;
  floatx4 acc[2];
  acc[0] = (floatx4)0.f;
  acc[1] = (floatx4)0.f;
  int kbase = w * 512;
#pragma unroll 4
  for (int it = 0; it < 16; ++it) {
    int k = kbase + it * 32 + quad * 8;
    float4 sm0 = *(const float4*)(smooth + k);
    float4 sm1 = *(const float4*)(smooth + k + 4);
    short8 bfrag[2];
#pragma unroll
    for (int nt = 0; nt < 2; ++nt)
      bfrag[nt] = *(const short8*)(ldT + (size_t)(nt * 16 + l16) * K_IN + k);
    const float* xr = x + (size_t)(rowbase + l16) * K_IN + k;
    float4 x0 = *(const float4*)xr;
    float4 x1 = *(const float4*)(xr + 4);
    short8 af;
    af[0] = (short)f2bf(x0.x * sm0.x); af[1] = (short)f2bf(x0.y * sm0.y);
    af[2] = (short)f2bf(x0.z * sm0.z); af[3] = (short)f2bf(x0.w * sm0.w);
    af[4] = (short)f2bf(x1.x * sm1.x); af[5] = (short)f2bf(x1.y * sm1.y);
    af[6] = (short)f2bf(x1.z * sm1.z); af[7] = (short)f2bf(x1.w * sm1.w);
#pragma unroll
    for (int nt = 0; nt < 2; ++nt)
      acc[nt] = __builtin_amdgcn_mfma_f32_16x16x32_bf16(af, bfrag[nt], acc[nt], 0, 0, 0);
  }
  // C layout: row (A/x index) = quad*4 + r, col (B/rank index) = l16
#pragma unroll
  for (int nt = 0; nt < 2; ++nt)
#pragma unroll
    for (int r = 0; r < 4; ++r)
      red[w][quad * 4 + r][nt * 16 + l16] = acc[nt][r];
  __syncthreads();
  if (tid < 128) {
    int rl = tid >> 3, seg = tid & 7;  // row 0..15, col segment of 4
    ushort4v o;
#pragma unroll
    for (int j = 0; j < 4; ++j) {
      int c = seg * 4 + j;
      float s = red[0][rl][c] + red[1][rl][c] + red[2][rl][c] + red[3][rl][c];
      o[j] = f2bf(s);
    }
    *(ushort4v*)(Xcat + (size_t)(rowbase + rl) * KC + 2048 + seg * 4) = o;
  }
}

// ---------------- K3: main GEMM: out = Xcat @ Wcat^T + bias ----------------
__device__ __forceinline__ void gld_lds16(const unsigned short* g, unsigned short* l) {
  __builtin_amdgcn_global_load_lds(
      (const __attribute__((address_space(1))) unsigned int*)g,
      (__attribute__((address_space(3))) unsigned int*)l, 16, 0, 0);
}

__global__ __launch_bounds__(256) void gemm_kernel(const unsigned short* __restrict__ Xcat,
                                                   const unsigned short* __restrict__ Wcat,
                                                   const float* __restrict__ bias,
                                                   float* __restrict__ out) {
  __shared__ unsigned short smem[16384];  // A: 128x64, B: 128x64 bf16 (32 KiB)
  unsigned short* smemA = smem;
  unsigned short* smemB = smem + 8192;
  int tid = threadIdx.x;
  int w = tid >> 6, lane = tid & 63, quad = lane >> 4, l16 = lane & 15;
  int wm = w >> 1, wn = w & 1;
  int bM = blockIdx.y * 128, bN = blockIdx.x * 128;

  // staging: thread -> (row = tid/8, chunk pos = tid%8), fetch XOR-swizzled chunk
  int srow = tid >> 3;
  int cs = (tid & 7) ^ (srow & 7);
  const unsigned short* Ag = Xcat + (size_t)(bM + srow) * KC + cs * 8;
  const unsigned short* Bg = Wcat + (size_t)(bN + srow) * KC + cs * 8;

  // fragment LDS offsets (ushort units). row&7 == l16&7 for all tiles.
  int c0 = (quad ^ (l16 & 7)) * 8;
  int c1 = ((4 + quad) ^ (l16 & 7)) * 8;
  int arow[4], brow[4];
#pragma unroll
  for (int mt = 0; mt < 4; ++mt) arow[mt] = (wm * 64 + mt * 16 + l16) * 64;
#pragma unroll
  for (int nt = 0; nt < 4; ++nt) brow[nt] = (wn * 64 + nt * 16 + l16) * 64;

  floatx4 acc[4][4];
#pragma unroll
  for (int mt = 0; mt < 4; ++mt)
#pragma unroll
    for (int nt = 0; nt < 4; ++nt) acc[mt][nt] = (floatx4)0.f;

  for (int kt = 0; kt < 33; ++kt) {
    int k0 = kt * 64;
#pragma unroll
    for (int rd = 0; rd < 4; ++rd) {
      gld_lds16(Ag + (size_t)rd * 32 * KC + k0, smemA + rd * 2048 + w * 512);
      gld_lds16(Bg + (size_t)rd * 32 * KC + k0, smemB + rd * 2048 + w * 512);
    }
    __syncthreads();  // drains vmcnt (global_load_lds) before reads

    short8 af[4][2], bf[4][2];
#pragma unroll
    for (int mt = 0; mt < 4; ++mt) {
      af[mt][0] = *(const short8*)(smemA + arow[mt] + c0);
      af[mt][1] = *(const short8*)(smemA + arow[mt] + c1);
    }
#pragma unroll
    for (int nt = 0; nt < 4; ++nt) {
      bf[nt][0] = *(const short8*)(smemB + brow[nt] + c0);
      bf[nt][1] = *(const short8*)(smemB + brow[nt] + c1);
    }
#pragma unroll
    for (int kb = 0; kb < 2; ++kb)
#pragma unroll
      for (int mt = 0; mt < 4; ++mt)
#pragma unroll
        for (int nt = 0; nt < 4; ++nt)
          acc[mt][nt] = __builtin_amdgcn_mfma_f32_16x16x32_bf16(af[mt][kb], bf[nt][kb],
                                                                acc[mt][nt], 0, 0, 0);
    __syncthreads();  // protect LDS before next stage
  }

  // epilogue: + bias, store fp32
#pragma unroll
  for (int nt = 0; nt < 4; ++nt) {
    int col = bN + wn * 64 + nt * 16 + l16;
    float bv = bias[col];
#pragma unroll
    for (int mt = 0; mt < 4; ++mt) {
      int row = bM + wm * 64 + mt * 16 + quad * 4;
#pragma unroll
      for (int r = 0; r < 4; ++r)
        out[(size_t)(row + r) * N_OUT + col] = acc[mt][nt][r] + bv;
    }
  }
}

extern "C" void kernel_launch(void* const* d_in, const int* in_sizes, int n_in,
                              void* d_out, int out_size, void* d_ws, size_t ws_size,
                              hipStream_t stream) {
  const float* x      = (const float*)d_in[0];
  const float* wgt    = (const float*)d_in[1];
  const float* ld     = (const float*)d_in[2];
  const float* lup    = (const float*)d_in[3];
  const float* smooth = (const float*)d_in[4];
  const float* bias   = (const float*)d_in[5];
  float* out = (float*)d_out;

  unsigned short* Xcat = (unsigned short*)d_ws;                 // 8192*2112*2 = 34.6 MB
  unsigned short* Wcat = Xcat + (size_t)M_TOK * KC;             //  8.65 MB
  unsigned short* ldT  = Wcat + (size_t)N_OUT * KC;             //  128 KB

  hipLaunchKernelGGL(ldt_kernel,     dim3(256),    dim3(256), 0, stream, ld, ldT);
  hipLaunchKernelGGL(quant_x_kernel, dim3(M_TOK),  dim3(256), 0, stream, x, smooth, Xcat);
  hipLaunchKernelGGL(quant_w_kernel, dim3(N_OUT),  dim3(256), 0, stream, wgt, lup, Wcat);
  hipLaunchKernelGGL(lowrank_kernel, dim3(M_TOK/16), dim3(256), 0, stream, x, smooth, ldT, Xcat);
  hipLaunchKernelGGL(gemm_kernel,    dim3(N_OUT/128, M_TOK/128), dim3(256), 0, stream,
                     Xcat, Wcat, bias, out);
}